// Round 20
// baseline (129.679 us; speedup 1.0000x reference)
//
#include <hip/hip_runtime.h>

typedef __bf16 bf16x8 __attribute__((ext_vector_type(8)));
typedef float f32x4 __attribute__((ext_vector_type(4)));

#define NEG_SLOPE 0.01f
#define BN_EPS 1e-5f

static __device__ __forceinline__ unsigned short f2bf(float f) {
    unsigned u = __builtin_bit_cast(unsigned, f);
    unsigned r = (u + 0x7fffu + ((u >> 16) & 1u)) >> 16;
    return (unsigned short)r;
}
static __device__ __forceinline__ float bf2f(unsigned short s) {
    return __builtin_bit_cast(float, (unsigned)s << 16);
}
static __device__ __forceinline__ float lrelu(float v) {
    return fmaxf(v, 0.f) + NEG_SLOPE * fminf(v, 0.f);
}
static __device__ __forceinline__ f32x4 bn4(f32x4 v, f32x4 sc, f32x4 sh) {
    f32x4 r = v * sc + sh;
    r.x = lrelu(r.x); r.y = lrelu(r.y); r.z = lrelu(r.z); r.w = lrelu(r.w);
    return r;
}

// ---- prep: W swizzle to fragment order + dst histogram + zero stats ----
__global__ __launch_bounds__(256) void prep(const float* __restrict__ We0,
                                            const float* __restrict__ We1,
                                            unsigned short* __restrict__ wbs0,
                                            unsigned short* __restrict__ wbs1,
                                            float* __restrict__ stats,
                                            const int* __restrict__ dst,
                                            int* __restrict__ hist, int E) {
    const int idx = blockIdx.x * 256 + threadIdx.x;
    if (blockIdx.x == 0) stats[threadIdx.x] = 0.f;      // stats[0..255]
    if (idx < 65536) {
        const int t = idx;                         // 0..65535
        const float* We = (t >> 15) ? We1 : We0;
        unsigned short* wbs = (t >> 15) ? wbs1 : wbs0;
        const int r = t & 32767;                   // [i:6][os:2][h:1][l:6]
        const int i = r >> 9, os = (r >> 7) & 3, h = (r >> 6) & 1, l = r & 63;
        const float* sp = We + (size_t)(i * 64 + 16 * os + (l & 15)) * 64
                             + h * 32 + 8 * (l >> 4);
        const f32x4 v0 = *reinterpret_cast<const f32x4*>(sp);
        const f32x4 v1 = *reinterpret_cast<const f32x4*>(sp + 4);
        ushort4 u0, u1;
        u0.x = f2bf(v0.x); u0.y = f2bf(v0.y); u0.z = f2bf(v0.z); u0.w = f2bf(v0.w);
        u1.x = f2bf(v1.x); u1.y = f2bf(v1.y); u1.z = f2bf(v1.z); u1.w = f2bf(v1.w);
        *reinterpret_cast<ushort4*>(wbs + (size_t)r * 8) = u0;
        *reinterpret_cast<ushort4*>(wbs + (size_t)r * 8 + 4) = u1;
    } else {
        const int e = idx - 65536;                 // 0..E-1
        if (e < E) atomicAdd(&hist[dst[e]], 1);
    }
}

// ---- exclusive prefix sum over hist[0..N) -> ofs[0..N], cur copy (1 block) ----
__global__ __launch_bounds__(256) void scan_kernel(const int* __restrict__ hist,
                                                   int* __restrict__ ofs,
                                                   int* __restrict__ cur, int N) {
    __shared__ int wsum[4];
    const int tid = threadIdx.x;
    const int per = N / 256;                       // 32
    const int base = tid * per;
    int loc[32];
    int s = 0;
#pragma unroll
    for (int k = 0; k < 32; ++k) { loc[k] = s; s += hist[base + k]; }
    const int lane = tid & 63, w = tid >> 6;
    int run = s;
#pragma unroll
    for (int d = 1; d < 64; d <<= 1) {
        int up = __shfl_up(run, d, 64);
        if (lane >= d) run += up;
    }
    const int excl = run - s;
    if (lane == 63) wsum[w] = run;
    __syncthreads();
    int woff = 0;
#pragma unroll
    for (int i = 0; i < 4; ++i) woff += (i < w) ? wsum[i] : 0;
    if (tid == 255) ofs[N] = woff + run;
    const int off = woff + excl;
#pragma unroll
    for (int k = 0; k < 32; ++k) {
        ofs[base + k] = off + loc[k];
        cur[base + k] = off + loc[k];
    }
}

// ---- scatter + reorder fused: assign CSR slot, copy ef row (bf16) + src ----
__global__ __launch_bounds__(256) void scatter_reorder(
    const int* __restrict__ dst, const int* __restrict__ src,
    const float* __restrict__ ef, int* __restrict__ cur,
    unsigned short* __restrict__ ef_bs, int* __restrict__ src_s) {
    const int e = blockIdx.x * 256 + threadIdx.x;
    const int p = atomicAdd(&cur[dst[e]], 1);
    src_s[p] = src[e];
    const float* er = ef + (size_t)e * 64;
    unsigned short* orow = ef_bs + (size_t)p * 64;
#pragma unroll
    for (int c = 0; c < 16; ++c) {
        const f32x4 v = *reinterpret_cast<const f32x4*>(er + 4 * c);
        ushort4 u;
        u.x = f2bf(v.x); u.y = f2bf(v.y); u.z = f2bf(v.z); u.w = f2bf(v.w);
        *reinterpret_cast<ushort4*>(orow + 4 * c) = u;
    }
}

// ---- dual node matmul: aggr = BN(x)@Wr + br ; NB = BN(x)@be ;
//      ALSO writes xb = bf16(BN(x)) for msg_fused. ----
__global__ __launch_bounds__(256) void node_mm2(
    const float* __restrict__ x,
    const float* __restrict__ Wr, const float* __restrict__ br,
    const float* __restrict__ be,
    float* __restrict__ aggr, float* __restrict__ NB,
    unsigned short* __restrict__ xb,
    const float* __restrict__ sums, const float* __restrict__ gamma,
    const float* __restrict__ beta, float invN) {
    __shared__ float Ml[64][64];
    __shared__ float Bl[64][64];
    __shared__ float xl[64][64];
    __shared__ float ssl[128];
    const int tid = threadIdx.x;
    if (sums) {
        if (tid < 64) {
            const float mean = sums[tid] * invN;
            const float var  = sums[64 + tid] * invN - mean * mean;
            const float sc = gamma[tid] * rsqrtf(var + BN_EPS);
            ssl[tid] = sc;
            ssl[64 + tid] = beta[tid] - mean * sc;
        }
        __syncthreads();
    }
    const int n0 = blockIdx.x * 64;
    for (int f = tid; f < 1024; f += 256) {
        int r = f >> 4, c = f & 15;
        *reinterpret_cast<float4*>(&Ml[r][c * 4]) =
            *reinterpret_cast<const float4*>(Wr + (size_t)r * 64 + c * 4);
        *reinterpret_cast<float4*>(&Bl[r][c * 4]) =
            *reinterpret_cast<const float4*>(be + (size_t)r * 64 + c * 4);
        f32x4 xv = *reinterpret_cast<const f32x4*>(x + (size_t)(n0 + r) * 64 + c * 4);
        if (sums) {
            const f32x4 sc = *reinterpret_cast<const f32x4*>(&ssl[c * 4]);
            const f32x4 sh = *reinterpret_cast<const f32x4*>(&ssl[64 + c * 4]);
            xv = bn4(xv, sc, sh);
        }
        *reinterpret_cast<f32x4*>(&xl[r][c * 4]) = xv;
        ushort4 u;
        u.x = f2bf(xv.x); u.y = f2bf(xv.y); u.z = f2bf(xv.z); u.w = f2bf(xv.w);
        *reinterpret_cast<ushort4*>(xb + (size_t)(n0 + r) * 64 + c * 4) = u;
    }
    __syncthreads();
    const int o = tid & 63, g = tid >> 6;
    float accA[16] = {}, accB[16] = {};
    for (int i4 = 0; i4 < 16; ++i4) {
        float m0 = Ml[4 * i4 + 0][o], m1 = Ml[4 * i4 + 1][o];
        float m2 = Ml[4 * i4 + 2][o], m3 = Ml[4 * i4 + 3][o];
        float b0 = Bl[4 * i4 + 0][o], b1 = Bl[4 * i4 + 1][o];
        float b2 = Bl[4 * i4 + 2][o], b3 = Bl[4 * i4 + 3][o];
#pragma unroll
        for (int k = 0; k < 16; ++k) {
            const f32x4 xv = *reinterpret_cast<const f32x4*>(&xl[g + 4 * k][4 * i4]);
            accA[k] += xv.x * m0 + xv.y * m1 + xv.z * m2 + xv.w * m3;
            accB[k] += xv.x * b0 + xv.y * b1 + xv.z * b2 + xv.w * b3;
        }
    }
    const float b = br[o];
#pragma unroll
    for (int k = 0; k < 16; ++k) {
        aggr[(size_t)(n0 + g + 4 * k) * 64 + o] = accA[k] + b;
        NB[(size_t)(n0 + g + 4 * k) * 64 + o]   = accB[k];
    }
}

// ---- fused NNConv message: 64 edges/block, 256 thr / 4 waves (wave = os),
// double-buffered wlds, LDS 72.5KB -> 2 blocks/CU co-resident (barrier overlap).
// Reads pre-BN'd bf16 xb; outputs bf16 msg in CSR order.
__global__ __launch_bounds__(256, 2) void msg_fused(
    const unsigned short* __restrict__ ef_bs,  // [E][64] bf16, CSR order
    const unsigned short* __restrict__ wbs,    // fragment-order [i][os][h][l][8]
    const unsigned short* __restrict__ xb,     // [N][64] bf16 (BN applied)
    const float* __restrict__ NB,              // [N][64] f32
    const int* __restrict__ src_s,             // [E] src ids, CSR order
    unsigned short* __restrict__ msg) {        // [E][64] bf16 out, CSR order
    __shared__ unsigned short wlds[32768];     // 2 x 32KB chunk buffers
    __shared__ unsigned short xT2[64 * 68];    // bf16 [e][i], stride 68 (8.5KB)
    const int tid = threadIdx.x;
    const int e0 = blockIdx.x * 64;

    // gather xb rows of the 64 src nodes -> xT2[e][i] (bf16 copy)
#pragma unroll
    for (int it = 0; it < 2; ++it) {
        int f = it * 256 + tid;                // 0..511 = 64e x 8 groups
        int e = f & 63, c8 = f >> 6;           // c8 in 0..7
        int s = src_s[e0 + e];
        const ushort4 v0 = *reinterpret_cast<const ushort4*>(xb + (size_t)s * 64 + c8 * 8);
        const ushort4 v1 = *reinterpret_cast<const ushort4*>(xb + (size_t)s * 64 + c8 * 8 + 4);
        *reinterpret_cast<ushort4*>(&xT2[e * 68 + c8 * 8])     = v0;
        *reinterpret_cast<ushort4*>(&xT2[e * 68 + c8 * 8 + 4]) = v1;
    }

    const int w = tid >> 6, l = tid & 63, lg = l >> 4, ln = l & 15;
    const int os = w;                          // wave = o-slice

    // ef B-frags: wave covers all 4 edge-tiles of the block (held in regs)
    bf16x8 B0[4], B1[4];
#pragma unroll
    for (int tt = 0; tt < 4; ++tt) {
        const unsigned short* pe = ef_bs + (size_t)(e0 + 16 * tt + ln) * 64 + 8 * lg;
        B0[tt] = *reinterpret_cast<const bf16x8*>(pe);
        B1[tt] = *reinterpret_cast<const bf16x8*>(pe + 32);
    }

    // T14 register staging of 4-i full-o chunks (32KB = 256 thr x 8 x 16B)
    const char* gW = (const char*)wbs;
    char* wldsB = (char*)wlds;
#define GLD(c, j) (*reinterpret_cast<const bf16x8*>(gW + (size_t)(c) * 32768 + (j) * 4096 + tid * 16))
#define SST(b, j, v) (*reinterpret_cast<bf16x8*>(wldsB + (b) * 32768 + (j) * 4096 + tid * 16) = (v))

    bf16x8 S0 = GLD(0, 0), S1 = GLD(0, 1), S2 = GLD(0, 2), S3 = GLD(0, 3);
    bf16x8 S4 = GLD(0, 4), S5 = GLD(0, 5), S6 = GLD(0, 6), S7 = GLD(0, 7);
    SST(0, 0, S0); SST(0, 1, S1); SST(0, 2, S2); SST(0, 3, S3);
    SST(0, 4, S4); SST(0, 5, S5); SST(0, 6, S6); SST(0, 7, S7);
    S0 = GLD(1, 0); S1 = GLD(1, 1); S2 = GLD(1, 2); S3 = GLD(1, 3);
    S4 = GLD(1, 4); S5 = GLD(1, 5); S6 = GLD(1, 6); S7 = GLD(1, 7);
    __syncthreads();   // xT2 + chunk-0 visible

    f32x4 acc[4] = {};
    const int wofs = os * 1024 + l * 8;
    for (int t = 0; t < 16; ++t) {
        const unsigned short* wb_ = wlds + (t & 1) * 16384 + wofs;
        // per-tile x scalars for i = 4t..4t+3 (bf16 -> f32)
        f32x4 xsv[4];
#pragma unroll
        for (int tt = 0; tt < 4; ++tt) {
            const ushort4 xu = *reinterpret_cast<const ushort4*>(
                &xT2[(16 * tt + ln) * 68 + 4 * t]);
            xsv[tt].x = bf2f(xu.x); xsv[tt].y = bf2f(xu.y);
            xsv[tt].z = bf2f(xu.z); xsv[tt].w = bf2f(xu.w);
        }
#pragma unroll
        for (int ii = 0; ii < 4; ++ii) {
            const bf16x8 A0 = *reinterpret_cast<const bf16x8*>(wb_ + ii * 4096);
            const bf16x8 A1 = *reinterpret_cast<const bf16x8*>(wb_ + ii * 4096 + 512);
#pragma unroll
            for (int tt = 0; tt < 4; ++tt) {
                f32x4 c = {};
                c = __builtin_amdgcn_mfma_f32_16x16x32_bf16(A0, B0[tt], c, 0, 0, 0);
                c = __builtin_amdgcn_mfma_f32_16x16x32_bf16(A1, B1[tt], c, 0, 0, 0);
                acc[tt] += xsv[tt][ii] * c;
            }
        }
        if (t < 15) {
            const int nb = (t + 1) & 1;
            SST(nb, 0, S0); SST(nb, 1, S1); SST(nb, 2, S2); SST(nb, 3, S3);
            SST(nb, 4, S4); SST(nb, 5, S5); SST(nb, 6, S6); SST(nb, 7, S7);
            if (t < 14) {
                S0 = GLD(t + 2, 0); S1 = GLD(t + 2, 1);
                S2 = GLD(t + 2, 2); S3 = GLD(t + 2, 3);
                S4 = GLD(t + 2, 4); S5 = GLD(t + 2, 5);
                S6 = GLD(t + 2, 6); S7 = GLD(t + 2, 7);
            }
        }
        __syncthreads();   // single barrier per chunk
    }
#undef GLD
#undef SST

    // epilogue: add NB[src][o-slice], store bf16 to msg (CSR order)
#pragma unroll
    for (int tt = 0; tt < 4; ++tt) {
        const int e = e0 + 16 * tt + ln;
        const int s = src_s[e];
        const f32x4 nbv = *reinterpret_cast<const f32x4*>(NB + (size_t)s * 64 + os * 16 + 4 * lg);
        const f32x4 add = acc[tt] + nbv;
        ushort4 u;
        u.x = f2bf(add.x); u.y = f2bf(add.y); u.z = f2bf(add.z); u.w = f2bf(add.w);
        *reinterpret_cast<ushort4*>(msg + (size_t)e * 64 + os * 16 + 4 * lg) = u;
    }
}

// ---- gather: node v sums its CONTIGUOUS bf16 msg rows (no fence, no stats) ----
__global__ __launch_bounds__(256) void gather_k(const unsigned short* __restrict__ msg,
                                                const int* __restrict__ ofs,
                                                float* __restrict__ aggr) {
    const int tid = threadIdx.x;
    const int w = tid >> 6, lane = tid & 63;
    const int v = blockIdx.x * 4 + w;
    const int beg = ofs[v], end = ofs[v + 1];
    float a0 = 0.f, a1 = 0.f, a2 = 0.f, a3 = 0.f;
    int j = beg;
    for (; j + 4 <= end; j += 4) {
        a0 += bf2f(msg[(size_t)(j + 0) * 64 + lane]);
        a1 += bf2f(msg[(size_t)(j + 1) * 64 + lane]);
        a2 += bf2f(msg[(size_t)(j + 2) * 64 + lane]);
        a3 += bf2f(msg[(size_t)(j + 3) * 64 + lane]);
    }
    for (; j < end; ++j) a0 += bf2f(msg[(size_t)j * 64 + lane]);
    aggr[(size_t)v * 64 + lane] += (a0 + a1) + (a2 + a3);
}

// ---- BN partial sums only: 64 blocks, atomics, NO fence, NO finalize ----
__global__ __launch_bounds__(256) void bn_stats(const float* __restrict__ h,
                                                float* __restrict__ sums) {
    const int tid = threadIdx.x;
    const int o = tid & 63, g = tid >> 6;
    const int n0 = blockIdx.x * 128;
    float s = 0.f, s2 = 0.f;
    for (int k = 0; k < 32; ++k) {
        float v = h[(size_t)(n0 + g * 32 + k) * 64 + o];
        s += v; s2 += v * v;
    }
    __shared__ float red[2][4][64];
    red[0][g][o] = s; red[1][g][o] = s2;
    __syncthreads();
    if (g == 0) {
        s  = red[0][0][o] + red[0][1][o] + red[0][2][o] + red[0][3][o];
        s2 = red[1][0][o] + red[1][1][o] + red[1][2][o] + red[1][3][o];
        atomicAdd(&sums[o], s);
        atomicAdd(&sums[64 + o], s2);
    }
}

// ---- final: out[n,q] = sum_o BN(x)[n,o]*W_lin[q,o] + b_lin[q] ----
__global__ __launch_bounds__(256) void out_kernel(
    const float* __restrict__ x2, const float* __restrict__ Wl,
    const float* __restrict__ bl, float* __restrict__ out,
    const float* __restrict__ sums, const float* __restrict__ gamma,
    const float* __restrict__ beta, float invN) {
    __shared__ float Wt[64][129];
    __shared__ float xl[64][64];
    __shared__ float ssl[128];
    const int tid = threadIdx.x;
    if (tid < 64) {
        const float mean = sums[tid] * invN;
        const float var  = sums[64 + tid] * invN - mean * mean;
        const float sc = gamma[tid] * rsqrtf(var + BN_EPS);
        ssl[tid] = sc;
        ssl[64 + tid] = beta[tid] - mean * sc;
    }
    __syncthreads();
    const int n0 = blockIdx.x * 64;
    for (int f = tid; f < 8192; f += 256) {
        int q = f >> 6, o = f & 63;
        Wt[o][q] = Wl[f];
    }
    for (int f = tid; f < 1024; f += 256) {
        int r = f >> 4, c = f & 15;
        f32x4 xv = *reinterpret_cast<const f32x4*>(x2 + (size_t)(n0 + r) * 64 + c * 4);
        const f32x4 sc = *reinterpret_cast<const f32x4*>(&ssl[c * 4]);
        const f32x4 sh = *reinterpret_cast<const f32x4*>(&ssl[64 + c * 4]);
        xv = bn4(xv, sc, sh);
        *reinterpret_cast<f32x4*>(&xl[r][c * 4]) = xv;
    }
    __syncthreads();
    const int q = tid & 127, ng = tid >> 7;
    float acc[32] = {};
    for (int o4 = 0; o4 < 16; ++o4) {
        float w0 = Wt[4 * o4 + 0][q], w1 = Wt[4 * o4 + 1][q];
        float w2 = Wt[4 * o4 + 2][q], w3 = Wt[4 * o4 + 3][q];
#pragma unroll
        for (int k = 0; k < 32; ++k) {
            const f32x4 xv = *reinterpret_cast<const f32x4*>(&xl[ng + 2 * k][4 * o4]);
            acc[k] += xv.x * w0 + xv.y * w1 + xv.z * w2 + xv.w * w3;
        }
    }
    const float b = bl[q];
#pragma unroll
    for (int k = 0; k < 32; ++k)
        out[(size_t)(n0 + ng + 2 * k) * 128 + q] = acc[k] + b;
}

extern "C" void kernel_launch(void* const* d_in, const int* in_sizes, int n_in,
                              void* d_out, int out_size, void* d_ws, size_t ws_size,
                              hipStream_t stream) {
    const float* nf      = (const float*)d_in[0];
    const int*   ei      = (const int*)d_in[1];
    const float* ef      = (const float*)d_in[2];
    const float* W_edge0 = (const float*)d_in[4];
    const float* b_edge0 = (const float*)d_in[5];
    const float* W_root0 = (const float*)d_in[6];
    const float* b_root0 = (const float*)d_in[7];
    const float* gamma0  = (const float*)d_in[8];
    const float* beta0   = (const float*)d_in[9];
    const float* W_edge1 = (const float*)d_in[10];
    const float* b_edge1 = (const float*)d_in[11];
    const float* W_root1 = (const float*)d_in[12];
    const float* b_root1 = (const float*)d_in[13];
    const float* gamma1  = (const float*)d_in[14];
    const float* beta1   = (const float*)d_in[15];
    const float* W_lin   = (const float*)d_in[16];
    const float* b_lin   = (const float*)d_in[17];

    const int N = in_sizes[0] / 64;   // 8192
    const int E = in_sizes[1] / 2;    // 32768
    const int* src = ei;
    const int* dst = ei + E;

    unsigned short* ef_bs = (unsigned short*)d_ws;         // E*64 shorts (CSR)
    unsigned short* wbs0  = ef_bs + (size_t)E * 64;        // 262144
    unsigned short* wbs1  = wbs0 + 262144;                 // 262144
    unsigned short* msg   = wbs1 + 262144;                 // E*64 bf16 (CSR)
    unsigned short* xbuf  = msg + (size_t)E * 64;          // N*64 bf16
    float* aggr0 = (float*)(xbuf + (size_t)N * 64);        // N*64
    float* aggr1 = aggr0 + (size_t)N * 64;                 // N*64
    float* NBbuf = aggr1 + (size_t)N * 64;                 // N*64
    float* stats = NBbuf + (size_t)N * 64;                 // 256
    int*   hist  = (int*)(stats + 256);                    // N
    int*   ofs   = hist + N;                               // N+1
    int*   cur   = ofs + N + 1;                            // N
    int*   src_s = cur + N;                                // E

    const float invN = 1.0f / (float)N;

    hipMemsetAsync(hist, 0, N * sizeof(int), stream);
    prep<<<(65536 + E) / 256, 256, 0, stream>>>(W_edge0, W_edge1, wbs0, wbs1,
                                                stats, dst, hist, E);
    scan_kernel<<<1, 256, 0, stream>>>(hist, ofs, cur, N);
    scatter_reorder<<<E / 256, 256, 0, stream>>>(dst, src, ef, cur, ef_bs, src_s);

    // ---- layer 0 ----
    node_mm2<<<N / 64, 256, 0, stream>>>(nf, W_root0, b_root0, b_edge0, aggr0, NBbuf,
                                         xbuf, nullptr, nullptr, nullptr, invN);
    msg_fused<<<E / 64, 256, 0, stream>>>(ef_bs, wbs0, xbuf, NBbuf, src_s, msg);
    gather_k<<<N / 4, 256, 0, stream>>>(msg, ofs, aggr0);
    bn_stats<<<N / 128, 256, 0, stream>>>(aggr0, stats);

    // ---- layer 1 (x1 = BN0(aggr0) applied inline from raw sums) ----
    node_mm2<<<N / 64, 256, 0, stream>>>(aggr0, W_root1, b_root1, b_edge1, aggr1, NBbuf,
                                         xbuf, stats, gamma0, beta0, invN);
    msg_fused<<<E / 64, 256, 0, stream>>>(ef_bs, wbs1, xbuf, NBbuf, src_s, msg);
    gather_k<<<N / 4, 256, 0, stream>>>(msg, ofs, aggr1);
    bn_stats<<<N / 128, 256, 0, stream>>>(aggr1, stats + 128);

    // ---- final linear (x2 = BN1(aggr1) inline) ----
    out_kernel<<<N / 64, 256, 0, stream>>>(aggr1, W_lin, b_lin, (float*)d_out,
                                           stats + 128, gamma1, beta1, invN);
}

// Round 21
// 126.600 us; speedup vs baseline: 1.0243x; 1.0243x over previous
//
#include <hip/hip_runtime.h>

typedef __bf16 bf16x8 __attribute__((ext_vector_type(8)));
typedef float f32x4 __attribute__((ext_vector_type(4)));

#define NEG_SLOPE 0.01f
#define BN_EPS 1e-5f

static __device__ __forceinline__ unsigned short f2bf(float f) {
    unsigned u = __builtin_bit_cast(unsigned, f);
    unsigned r = (u + 0x7fffu + ((u >> 16) & 1u)) >> 16;
    return (unsigned short)r;
}
static __device__ __forceinline__ float bf2f(unsigned short s) {
    return __builtin_bit_cast(float, (unsigned)s << 16);
}
static __device__ __forceinline__ float lrelu(float v) {
    return fmaxf(v, 0.f) + NEG_SLOPE * fminf(v, 0.f);
}
static __device__ __forceinline__ f32x4 bn4(f32x4 v, f32x4 sc, f32x4 sh) {
    f32x4 r = v * sc + sh;
    r.x = lrelu(r.x); r.y = lrelu(r.y); r.z = lrelu(r.z); r.w = lrelu(r.w);
    return r;
}

// ---- prep: W swizzle to fragment order + dst histogram + zero stats ----
__global__ __launch_bounds__(256) void prep(const float* __restrict__ We0,
                                            const float* __restrict__ We1,
                                            unsigned short* __restrict__ wbs0,
                                            unsigned short* __restrict__ wbs1,
                                            float* __restrict__ stats,
                                            const int* __restrict__ dst,
                                            int* __restrict__ hist, int E) {
    const int idx = blockIdx.x * 256 + threadIdx.x;
    if (blockIdx.x == 0) stats[threadIdx.x] = 0.f;      // stats[0..255]
    if (idx < 65536) {
        const int t = idx;                         // 0..65535
        const float* We = (t >> 15) ? We1 : We0;
        unsigned short* wbs = (t >> 15) ? wbs1 : wbs0;
        const int r = t & 32767;                   // [i:6][os:2][h:1][l:6]
        const int i = r >> 9, os = (r >> 7) & 3, h = (r >> 6) & 1, l = r & 63;
        const float* sp = We + (size_t)(i * 64 + 16 * os + (l & 15)) * 64
                             + h * 32 + 8 * (l >> 4);
        const f32x4 v0 = *reinterpret_cast<const f32x4*>(sp);
        const f32x4 v1 = *reinterpret_cast<const f32x4*>(sp + 4);
        ushort4 u0, u1;
        u0.x = f2bf(v0.x); u0.y = f2bf(v0.y); u0.z = f2bf(v0.z); u0.w = f2bf(v0.w);
        u1.x = f2bf(v1.x); u1.y = f2bf(v1.y); u1.z = f2bf(v1.z); u1.w = f2bf(v1.w);
        *reinterpret_cast<ushort4*>(wbs + (size_t)r * 8) = u0;
        *reinterpret_cast<ushort4*>(wbs + (size_t)r * 8 + 4) = u1;
    } else {
        const int e = idx - 65536;                 // 0..E-1
        if (e < E) atomicAdd(&hist[dst[e]], 1);
    }
}

// ---- exclusive prefix sum over hist[0..N) -> ofs[0..N], cur copy (1 block) ----
__global__ __launch_bounds__(256) void scan_kernel(const int* __restrict__ hist,
                                                   int* __restrict__ ofs,
                                                   int* __restrict__ cur, int N) {
    __shared__ int wsum[4];
    const int tid = threadIdx.x;
    const int per = N / 256;                       // 32
    const int base = tid * per;
    int loc[32];
    int s = 0;
#pragma unroll
    for (int k = 0; k < 32; ++k) { loc[k] = s; s += hist[base + k]; }
    const int lane = tid & 63, w = tid >> 6;
    int run = s;
#pragma unroll
    for (int d = 1; d < 64; d <<= 1) {
        int up = __shfl_up(run, d, 64);
        if (lane >= d) run += up;
    }
    const int excl = run - s;
    if (lane == 63) wsum[w] = run;
    __syncthreads();
    int woff = 0;
#pragma unroll
    for (int i = 0; i < 4; ++i) woff += (i < w) ? wsum[i] : 0;
    if (tid == 255) ofs[N] = woff + run;
    const int off = woff + excl;
#pragma unroll
    for (int k = 0; k < 32; ++k) {
        ofs[base + k] = off + loc[k];
        cur[base + k] = off + loc[k];
    }
}

// ---- scatter + reorder fused: assign CSR slot, copy ef row (bf16) + src ----
__global__ __launch_bounds__(256) void scatter_reorder(
    const int* __restrict__ dst, const int* __restrict__ src,
    const float* __restrict__ ef, int* __restrict__ cur,
    unsigned short* __restrict__ ef_bs, int* __restrict__ src_s) {
    const int e = blockIdx.x * 256 + threadIdx.x;
    const int p = atomicAdd(&cur[dst[e]], 1);
    src_s[p] = src[e];
    const float* er = ef + (size_t)e * 64;
    unsigned short* orow = ef_bs + (size_t)p * 64;
#pragma unroll
    for (int c = 0; c < 16; ++c) {
        const f32x4 v = *reinterpret_cast<const f32x4*>(er + 4 * c);
        ushort4 u;
        u.x = f2bf(v.x); u.y = f2bf(v.y); u.z = f2bf(v.z); u.w = f2bf(v.w);
        *reinterpret_cast<ushort4*>(orow + 4 * c) = u;
    }
}

// ---- dual node matmul: aggr = BN(x)@Wr + br AND NB = BN(x)@be, one pass ----
__global__ __launch_bounds__(256) void node_mm2(
    const float* __restrict__ x,
    const float* __restrict__ Wr, const float* __restrict__ br,
    const float* __restrict__ be,
    float* __restrict__ aggr, float* __restrict__ NB,
    const float* __restrict__ sums, const float* __restrict__ gamma,
    const float* __restrict__ beta, float invN) {
    __shared__ float Ml[64][64];
    __shared__ float Bl[64][64];
    __shared__ float xl[64][64];
    __shared__ float ssl[128];
    const int tid = threadIdx.x;
    if (sums) {
        if (tid < 64) {
            const float mean = sums[tid] * invN;
            const float var  = sums[64 + tid] * invN - mean * mean;
            const float sc = gamma[tid] * rsqrtf(var + BN_EPS);
            ssl[tid] = sc;
            ssl[64 + tid] = beta[tid] - mean * sc;
        }
        __syncthreads();
    }
    const int n0 = blockIdx.x * 64;
    for (int f = tid; f < 1024; f += 256) {
        int r = f >> 4, c = f & 15;
        *reinterpret_cast<float4*>(&Ml[r][c * 4]) =
            *reinterpret_cast<const float4*>(Wr + (size_t)r * 64 + c * 4);
        *reinterpret_cast<float4*>(&Bl[r][c * 4]) =
            *reinterpret_cast<const float4*>(be + (size_t)r * 64 + c * 4);
        f32x4 xv = *reinterpret_cast<const f32x4*>(x + (size_t)(n0 + r) * 64 + c * 4);
        if (sums) {
            const f32x4 sc = *reinterpret_cast<const f32x4*>(&ssl[c * 4]);
            const f32x4 sh = *reinterpret_cast<const f32x4*>(&ssl[64 + c * 4]);
            xv = bn4(xv, sc, sh);
        }
        *reinterpret_cast<f32x4*>(&xl[r][c * 4]) = xv;
    }
    __syncthreads();
    const int o = tid & 63, g = tid >> 6;
    float accA[16] = {}, accB[16] = {};
    for (int i4 = 0; i4 < 16; ++i4) {
        float m0 = Ml[4 * i4 + 0][o], m1 = Ml[4 * i4 + 1][o];
        float m2 = Ml[4 * i4 + 2][o], m3 = Ml[4 * i4 + 3][o];
        float b0 = Bl[4 * i4 + 0][o], b1 = Bl[4 * i4 + 1][o];
        float b2 = Bl[4 * i4 + 2][o], b3 = Bl[4 * i4 + 3][o];
#pragma unroll
        for (int k = 0; k < 16; ++k) {
            const f32x4 xv = *reinterpret_cast<const f32x4*>(&xl[g + 4 * k][4 * i4]);
            accA[k] += xv.x * m0 + xv.y * m1 + xv.z * m2 + xv.w * m3;
            accB[k] += xv.x * b0 + xv.y * b1 + xv.z * b2 + xv.w * b3;
        }
    }
    const float b = br[o];
#pragma unroll
    for (int k = 0; k < 16; ++k) {
        aggr[(size_t)(n0 + g + 4 * k) * 64 + o] = accA[k] + b;
        NB[(size_t)(n0 + g + 4 * k) * 64 + o]   = accB[k];
    }
}

// ---- fused NNConv message: 128 edges/block, 512 thr / 8 waves, 4-i chunks,
// double-buffered wlds (one barrier/chunk). Output msg in bf16 (CSR order).
// xT2 layout [i][eh][ln][tt] -> xs ds_read is 2-way-bank (free).
__global__ __launch_bounds__(512, 1) void msg_fused(
    const unsigned short* __restrict__ ef_bs,  // [E][64] bf16, CSR order
    const unsigned short* __restrict__ wbs,    // fragment-order [i][os][h][l][8]
    const float* __restrict__ x,               // [N][64] f32 (pre-BN if sums)
    const float* __restrict__ NB,              // [N][64] f32
    const int* __restrict__ src_s,             // [E] src ids, CSR order
    unsigned short* __restrict__ msg,          // [E][64] bf16 out, CSR order
    const float* __restrict__ sums, const float* __restrict__ gamma,
    const float* __restrict__ beta, float invN) {
    __shared__ unsigned short wlds[32768];     // 2 x 32KB chunk buffers
    __shared__ float xT2[8192];                // 32KB: [i][eh][ln][tt]
    __shared__ float ssl[128];
    const int tid = threadIdx.x;
    const int e0 = blockIdx.x * 128;
    if (sums) {
        if (tid < 64) {
            const float mean = sums[tid] * invN;
            const float var  = sums[64 + tid] * invN - mean * mean;
            const float sc = gamma[tid] * rsqrtf(var + BN_EPS);
            ssl[tid] = sc;
            ssl[64 + tid] = beta[tid] - mean * sc;
        }
        __syncthreads();
    }

    // gather x rows of the 128 src nodes -> xT2 (f32, BN on load)
#pragma unroll
    for (int it = 0; it < 4; ++it) {
        int f = it * 512 + tid;                // 0..2047
        int e = f & 127, c = f >> 7;           // c in 0..15
        int s = src_s[e0 + e];
        f32x4 xv = *reinterpret_cast<const f32x4*>(x + (size_t)s * 64 + c * 4);
        if (sums) {
            const f32x4 sc = *reinterpret_cast<const f32x4*>(&ssl[c * 4]);
            const f32x4 sh = *reinterpret_cast<const f32x4*>(&ssl[64 + c * 4]);
            xv = bn4(xv, sc, sh);
        }
        const int base = (e >> 6) * 64 + (e & 15) * 4 + ((e >> 4) & 3);
        xT2[(4 * c + 0) * 128 + base] = xv.x;
        xT2[(4 * c + 1) * 128 + base] = xv.y;
        xT2[(4 * c + 2) * 128 + base] = xv.z;
        xT2[(4 * c + 3) * 128 + base] = xv.w;
    }

    const int w = tid >> 6, l = tid & 63, lg = l >> 4, ln = l & 15;
    const int os = w & 3, eh = w >> 2;

    // ef B-frags: this wave's 4 edge tiles (of its 64-edge half)
    bf16x8 B0[4], B1[4];
#pragma unroll
    for (int tt = 0; tt < 4; ++tt) {
        const unsigned short* pe = ef_bs + (size_t)(e0 + 64 * eh + 16 * tt + ln) * 64 + 8 * lg;
        B0[tt] = *reinterpret_cast<const bf16x8*>(pe);
        B1[tt] = *reinterpret_cast<const bf16x8*>(pe + 32);
    }

    // T14 register staging of 4-i chunks (32KB = 512 thr x 4 x 16B)
    const char* gW = (const char*)wbs;
    char* wldsB = (char*)wlds;
#define GLD(c, j) (*reinterpret_cast<const bf16x8*>(gW + (size_t)(c) * 32768 + (j) * 8192 + tid * 16))
#define SST(b, j, v) (*reinterpret_cast<bf16x8*>(wldsB + (b) * 32768 + (j) * 8192 + tid * 16) = (v))

    bf16x8 S0 = GLD(0, 0), S1 = GLD(0, 1), S2 = GLD(0, 2), S3 = GLD(0, 3);
    SST(0, 0, S0); SST(0, 1, S1); SST(0, 2, S2); SST(0, 3, S3);
    S0 = GLD(1, 0); S1 = GLD(1, 1); S2 = GLD(1, 2); S3 = GLD(1, 3);
    __syncthreads();   // xT2 + chunk-0 visible

    f32x4 acc[4] = {};
    const int wofs = os * 1024 + l * 8;
    for (int t = 0; t < 16; ++t) {
        const unsigned short* wb_ = wlds + (t & 1) * 16384 + wofs;
#pragma unroll
        for (int ii = 0; ii < 4; ++ii) {
            const bf16x8 A0 = *reinterpret_cast<const bf16x8*>(wb_ + ii * 4096);
            const bf16x8 A1 = *reinterpret_cast<const bf16x8*>(wb_ + ii * 4096 + 512);
            const f32x4 xs = *reinterpret_cast<const f32x4*>(
                &xT2[(t * 4 + ii) * 128 + eh * 64 + ln * 4]);
#pragma unroll
            for (int tt = 0; tt < 4; ++tt) {
                f32x4 c = {};
                c = __builtin_amdgcn_mfma_f32_16x16x32_bf16(A0, B0[tt], c, 0, 0, 0);
                c = __builtin_amdgcn_mfma_f32_16x16x32_bf16(A1, B1[tt], c, 0, 0, 0);
                acc[tt] += xs[tt] * c;
            }
        }
        if (t < 15) {
            const int nb = (t + 1) & 1;
            SST(nb, 0, S0); SST(nb, 1, S1); SST(nb, 2, S2); SST(nb, 3, S3);
            if (t < 14) {
                S0 = GLD(t + 2, 0); S1 = GLD(t + 2, 1);
                S2 = GLD(t + 2, 2); S3 = GLD(t + 2, 3);
            }
        }
        __syncthreads();   // single barrier per chunk
    }
#undef GLD
#undef SST

    // epilogue: add NB[src][o-slice], store bf16 to msg (CSR order)
#pragma unroll
    for (int tt = 0; tt < 4; ++tt) {
        const int e = e0 + 64 * eh + 16 * tt + ln;
        const int s = src_s[e];
        const f32x4 nbv = *reinterpret_cast<const f32x4*>(NB + (size_t)s * 64 + os * 16 + 4 * lg);
        const f32x4 add = acc[tt] + nbv;
        ushort4 u;
        u.x = f2bf(add.x); u.y = f2bf(add.y); u.z = f2bf(add.z); u.w = f2bf(add.w);
        *reinterpret_cast<ushort4*>(msg + (size_t)e * 64 + os * 16 + 4 * lg) = u;
    }
}

// ---- gather: node v sums its CONTIGUOUS bf16 msg rows (no fence, no stats) ----
__global__ __launch_bounds__(256) void gather_k(const unsigned short* __restrict__ msg,
                                                const int* __restrict__ ofs,
                                                float* __restrict__ aggr) {
    const int tid = threadIdx.x;
    const int w = tid >> 6, lane = tid & 63;
    const int v = blockIdx.x * 4 + w;
    const int beg = ofs[v], end = ofs[v + 1];
    float a0 = 0.f, a1 = 0.f, a2 = 0.f, a3 = 0.f;
    int j = beg;
    for (; j + 4 <= end; j += 4) {
        a0 += bf2f(msg[(size_t)(j + 0) * 64 + lane]);
        a1 += bf2f(msg[(size_t)(j + 1) * 64 + lane]);
        a2 += bf2f(msg[(size_t)(j + 2) * 64 + lane]);
        a3 += bf2f(msg[(size_t)(j + 3) * 64 + lane]);
    }
    for (; j < end; ++j) a0 += bf2f(msg[(size_t)j * 64 + lane]);
    aggr[(size_t)v * 64 + lane] += (a0 + a1) + (a2 + a3);
}

// ---- BN partial sums only: 64 blocks, atomics, NO fence, NO finalize ----
__global__ __launch_bounds__(256) void bn_stats(const float* __restrict__ h,
                                                float* __restrict__ sums) {
    const int tid = threadIdx.x;
    const int o = tid & 63, g = tid >> 6;
    const int n0 = blockIdx.x * 128;
    float s = 0.f, s2 = 0.f;
    for (int k = 0; k < 32; ++k) {
        float v = h[(size_t)(n0 + g * 32 + k) * 64 + o];
        s += v; s2 += v * v;
    }
    __shared__ float red[2][4][64];
    red[0][g][o] = s; red[1][g][o] = s2;
    __syncthreads();
    if (g == 0) {
        s  = red[0][0][o] + red[0][1][o] + red[0][2][o] + red[0][3][o];
        s2 = red[1][0][o] + red[1][1][o] + red[1][2][o] + red[1][3][o];
        atomicAdd(&sums[o], s);
        atomicAdd(&sums[64 + o], s2);
    }
}

// ---- final: out[n,q] = sum_o BN(x)[n,o]*W_lin[q,o] + b_lin[q] ----
__global__ __launch_bounds__(256) void out_kernel(
    const float* __restrict__ x2, const float* __restrict__ Wl,
    const float* __restrict__ bl, float* __restrict__ out,
    const float* __restrict__ sums, const float* __restrict__ gamma,
    const float* __restrict__ beta, float invN) {
    __shared__ float Wt[64][129];
    __shared__ float xl[64][64];
    __shared__ float ssl[128];
    const int tid = threadIdx.x;
    if (tid < 64) {
        const float mean = sums[tid] * invN;
        const float var  = sums[64 + tid] * invN - mean * mean;
        const float sc = gamma[tid] * rsqrtf(var + BN_EPS);
        ssl[tid] = sc;
        ssl[64 + tid] = beta[tid] - mean * sc;
    }
    __syncthreads();
    const int n0 = blockIdx.x * 64;
    for (int f = tid; f < 8192; f += 256) {
        int q = f >> 6, o = f & 63;
        Wt[o][q] = Wl[f];
    }
    for (int f = tid; f < 1024; f += 256) {
        int r = f >> 4, c = f & 15;
        f32x4 xv = *reinterpret_cast<const f32x4*>(x2 + (size_t)(n0 + r) * 64 + c * 4);
        const f32x4 sc = *reinterpret_cast<const f32x4*>(&ssl[c * 4]);
        const f32x4 sh = *reinterpret_cast<const f32x4*>(&ssl[64 + c * 4]);
        xv = bn4(xv, sc, sh);
        *reinterpret_cast<f32x4*>(&xl[r][c * 4]) = xv;
    }
    __syncthreads();
    const int q = tid & 127, ng = tid >> 7;
    float acc[32] = {};
    for (int o4 = 0; o4 < 16; ++o4) {
        float w0 = Wt[4 * o4 + 0][q], w1 = Wt[4 * o4 + 1][q];
        float w2 = Wt[4 * o4 + 2][q], w3 = Wt[4 * o4 + 3][q];
#pragma unroll
        for (int k = 0; k < 32; ++k) {
            const f32x4 xv = *reinterpret_cast<const f32x4*>(&xl[ng + 2 * k][4 * o4]);
            acc[k] += xv.x * w0 + xv.y * w1 + xv.z * w2 + xv.w * w3;
        }
    }
    const float b = bl[q];
#pragma unroll
    for (int k = 0; k < 32; ++k)
        out[(size_t)(n0 + ng + 2 * k) * 128 + q] = acc[k] + b;
}

extern "C" void kernel_launch(void* const* d_in, const int* in_sizes, int n_in,
                              void* d_out, int out_size, void* d_ws, size_t ws_size,
                              hipStream_t stream) {
    const float* nf      = (const float*)d_in[0];
    const int*   ei      = (const int*)d_in[1];
    const float* ef      = (const float*)d_in[2];
    const float* W_edge0 = (const float*)d_in[4];
    const float* b_edge0 = (const float*)d_in[5];
    const float* W_root0 = (const float*)d_in[6];
    const float* b_root0 = (const float*)d_in[7];
    const float* gamma0  = (const float*)d_in[8];
    const float* beta0   = (const float*)d_in[9];
    const float* W_edge1 = (const float*)d_in[10];
    const float* b_edge1 = (const float*)d_in[11];
    const float* W_root1 = (const float*)d_in[12];
    const float* b_root1 = (const float*)d_in[13];
    const float* gamma1  = (const float*)d_in[14];
    const float* beta1   = (const float*)d_in[15];
    const float* W_lin   = (const float*)d_in[16];
    const float* b_lin   = (const float*)d_in[17];

    const int N = in_sizes[0] / 64;   // 8192
    const int E = in_sizes[1] / 2;    // 32768
    const int* src = ei;
    const int* dst = ei + E;

    unsigned short* ef_bs = (unsigned short*)d_ws;         // E*64 shorts (CSR)
    unsigned short* wbs0  = ef_bs + (size_t)E * 64;        // 262144
    unsigned short* wbs1  = wbs0 + 262144;                 // 262144
    unsigned short* msg   = wbs1 + 262144;                 // E*64 bf16 (CSR)
    float* aggr0 = (float*)(msg + (size_t)E * 64);         // N*64
    float* aggr1 = aggr0 + (size_t)N * 64;                 // N*64
    float* NBbuf = aggr1 + (size_t)N * 64;                 // N*64
    float* stats = NBbuf + (size_t)N * 64;                 // 256
    int*   hist  = (int*)(stats + 256);                    // N
    int*   ofs   = hist + N;                               // N+1
    int*   cur   = ofs + N + 1;                            // N
    int*   src_s = cur + N;                                // E

    const float invN = 1.0f / (float)N;

    hipMemsetAsync(hist, 0, N * sizeof(int), stream);
    prep<<<(65536 + E) / 256, 256, 0, stream>>>(W_edge0, W_edge1, wbs0, wbs1,
                                                stats, dst, hist, E);
    scan_kernel<<<1, 256, 0, stream>>>(hist, ofs, cur, N);
    scatter_reorder<<<E / 256, 256, 0, stream>>>(dst, src, ef, cur, ef_bs, src_s);

    // ---- layer 0 ----
    node_mm2<<<N / 64, 256, 0, stream>>>(nf, W_root0, b_root0, b_edge0, aggr0, NBbuf,
                                         nullptr, nullptr, nullptr, invN);
    msg_fused<<<E / 128, 512, 0, stream>>>(ef_bs, wbs0, nf, NBbuf, src_s, msg,
                                           nullptr, nullptr, nullptr, invN);
    gather_k<<<N / 4, 256, 0, stream>>>(msg, ofs, aggr0);
    bn_stats<<<N / 128, 256, 0, stream>>>(aggr0, stats);

    // ---- layer 1 (x1 = BN0(aggr0) applied inline from raw sums) ----
    node_mm2<<<N / 64, 256, 0, stream>>>(aggr0, W_root1, b_root1, b_edge1, aggr1, NBbuf,
                                         stats, gamma0, beta0, invN);
    msg_fused<<<E / 128, 512, 0, stream>>>(ef_bs, wbs1, aggr0, NBbuf, src_s, msg,
                                           stats, gamma0, beta0, invN);
    gather_k<<<N / 4, 256, 0, stream>>>(msg, ofs, aggr1);
    bn_stats<<<N / 128, 256, 0, stream>>>(aggr1, stats + 128);

    // ---- final linear (x2 = BN1(aggr1) inline) ----
    out_kernel<<<N / 64, 256, 0, stream>>>(aggr1, W_lin, b_lin, (float*)d_out,
                                           stats + 128, gamma1, beta1, invN);
}